// Round 7
// baseline (239.139 us; speedup 1.0000x reference)
//
#include <hip/hip_runtime.h>

#define NX 512
#define NY 512
#define XY (NX * NY)
#define LROW 264              // 4 left-halo + 256 main + 4 right-halo floats
#define NRC 24                // 8 rows x 3 comps
#define NCHUNK (NRC * 66)     // 1584 16B chunks per block

typedef float f4 __attribute__((ext_vector_type(4)));

#define GLOBAL_AS __attribute__((address_space(1)))
#define LDS_AS    __attribute__((address_space(3)))

// Max-concurrency single-barrier version.
// Evidence r0..r6: time tracks concurrent streams/CU, not traffic, not phase
// work. So: block = 4 rows x 256 y (y split in halves), 256 threads, s-tile
// 8 rows x 3 comps x 264 = 25.3 KB LDS -> 6 blocks/CU (24 waves, 75% occ,
// vs 36%). NO b_lds, NO barrier B: each thread computes its 14 b-values
// redundantly in registers from the s-tile (r0's verified math, sourced from
// LDS). One __syncthreads per block; afterwards blocks free-run, so 6
// independent streams interleave load-drain with compute.
// Costs accepted (proven non-binding): 2.1x read amp (r6: traffic lower,
// slower), ~2.5x VALU (r1 vs r3: phase work invisible at 15% busy).
// launch_bounds(256,6): VGPR cap ~341 >> ~90 live -> no spills (r2/r5 lesson).
__global__ __launch_bounds__(256, 6) void psi11t_kernel(
    const float* __restrict__ s,
    const float* __restrict__ t,
    const float* __restrict__ c0,
    float* __restrict__ out)
{
    __shared__ __align__(16) float s_lds[NRC * LROW];  // 25344 B

    // 8192 blocks; XCD swizzle: each XCD (D%8) gets 1024 consecutive gids
    // = 4 whole batches (L2 locality). 8192 % 8 == 0 -> bijective.
    const int D   = blockIdx.x;
    const int gid = (D & 7) * 1024 + (D >> 3);
    const int bidx  = gid >> 8;            // 32 batches (256 gids each)
    const int half  = (gid >> 7) & 1;      // y half
    const int strip = gid & 127;           // 128 strips of 4 rows
    const int x0  = strip * 4;
    const int yb0 = half * 256;

    const int tid = threadIdx.x;           // 256 threads
    const int r   = tid >> 6;              // 0..3: output row x0+r
    const int yl  = (tid & 63) * 4;        // 0..252: local y offset

    const float* sb = s + (size_t)bidx * 3 * XY;

    // ---- Phase 1: stage rows x0-2..x0+5 (+/-4 y-halo) via global_load_lds.
    // Linear LDS chunk k (16 B): rc = k/66 = c*8+R, col = (k%66)*4.
    // Global f4 source is 4-aligned and never straddles the y-wrap.
    auto stage = [&](int k) {
        const int rc  = k / 66;            // compiler magic-mul
        const int col = (k - rc * 66) * 4;
        const int c   = rc >> 3;
        const int R   = rc & 7;
        const int xg  = (x0 - 2 + R + NX) & (NX - 1);
        const int y   = (yb0 - 4 + col + NY) & (NY - 1);
        __builtin_amdgcn_global_load_lds(
            (const GLOBAL_AS void*)(sb + (size_t)c * XY + (size_t)xg * NY + y),
            (LDS_AS void*)&s_lds[rc * LROW + col], 16, 0, 0);
    };
    #pragma unroll
    for (int q = 0; q < 6; ++q) stage(tid + q * 256);
    if (tid < 48) stage(tid + 1536);

    const float coeff = 2.0f * t[0] * c0[0];
    __syncthreads();                       // the ONLY barrier

    // ---- Phase 2 (fused): redundant per-thread b in registers + output.
    // LDS row index: R = r + {0..4} <-> global rows x0+r-2 .. x0+r+2.
    f4 up[3], ce[3], dn[3];
    float pv3[3], nx0[3];
    f4 bu = {0.f, 0.f, 0.f, 0.f};          // b(x-1, yb..yb+3)
    f4 bc = {0.f, 0.f, 0.f, 0.f};          // b(x,   yb..yb+3)
    f4 bd = {0.f, 0.f, 0.f, 0.f};          // b(x+1, yb..yb+3)
    float bl = 0.f, br = 0.f;              // b(x, yb-1), b(x, yb+4)

    #pragma unroll
    for (int c = 0; c < 3; ++c) {
        const float* base = &s_lds[(c * 8) * LROW + 4 + yl];
        const float* Rm2 = base + (r    ) * LROW;
        const float* Rm1 = base + (r + 1) * LROW;
        const float* R0  = base + (r + 2) * LROW;
        const float* Rp1 = base + (r + 3) * LROW;
        const float* Rp2 = base + (r + 4) * LROW;

        const f4 ce_m2 = *(const f4*)Rm2;
        const f4 pv_m1 = *(const f4*)(Rm1 - 4);
        const f4 ce_m1 = *(const f4*)Rm1;
        const f4 nx_m1 = *(const f4*)(Rm1 + 4);
        const f4 pv_0  = *(const f4*)(R0 - 4);
        const f4 ce_0  = *(const f4*)R0;
        const f4 nx_0  = *(const f4*)(R0 + 4);
        const f4 pv_p1 = *(const f4*)(Rp1 - 4);
        const f4 ce_p1 = *(const f4*)Rp1;
        const f4 nx_p1 = *(const f4*)(Rp1 + 4);
        const f4 ce_p2 = *(const f4*)Rp2;

        // b(x-1): center row ce_m1, vertical ce_m2 + ce_0
        const f4 shl_m1 = {pv_m1[3], ce_m1[0], ce_m1[1], ce_m1[2]};
        const f4 shr_m1 = {ce_m1[1], ce_m1[2], ce_m1[3], nx_m1[0]};
        bu += ce_m1 * (ce_m2 + ce_0 + shl_m1 + shr_m1);

        // b(x): center row ce_0, vertical ce_m1 + ce_p1
        const f4 shl_0 = {pv_0[3], ce_0[0], ce_0[1], ce_0[2]};
        const f4 shr_0 = {ce_0[1], ce_0[2], ce_0[3], nx_0[0]};
        bc += ce_0 * (ce_m1 + ce_p1 + shl_0 + shr_0);

        // b(x+1): center row ce_p1, vertical ce_0 + ce_p2
        const f4 shl_p1 = {pv_p1[3], ce_p1[0], ce_p1[1], ce_p1[2]};
        const f4 shr_p1 = {ce_p1[1], ce_p1[2], ce_p1[3], nx_p1[0]};
        bd += ce_p1 * (ce_0 + ce_p2 + shl_p1 + shr_p1);

        // b(x, yb-1) and b(x, yb+4) scalars
        bl += pv_0[3] * (pv_m1[3] + pv_p1[3] + pv_0[2] + ce_0[0]);
        br += nx_0[0] * (nx_m1[0] + nx_p1[0] + nx_0[1] + ce_0[3]);

        up[c] = ce_m1; ce[c] = ce_0; dn[c] = ce_p1;
        pv3[c] = pv_0[3]; nx0[c] = nx_0[0];
    }

    const f4 bshl = {bl, bc[0], bc[1], bc[2]};
    const f4 bshr = {bc[1], bc[2], bc[3], br};

    f4 G[3];
    #pragma unroll
    for (int c = 0; c < 3; ++c) {
        const f4 shl = {pv3[c], ce[c][0], ce[c][1], ce[c][2]};
        const f4 shr = {ce[c][1], ce[c][2], ce[c][3], nx0[c]};
        const f4 Fs = up[c] + dn[c] + shl + shr;
        G[c] = Fs * bc + up[c] * bu + dn[c] * bd + shl * bshl + shr * bshr;
    }

    const f4 o0 = (ce[1] * G[2] - ce[2] * G[1]) * coeff;
    const f4 o1 = (ce[2] * G[0] - ce[0] * G[2]) * coeff;
    const f4 o2 = (ce[0] * G[1] - ce[1] * G[0]) * coeff;

    float* ob = out + (size_t)bidx * 3 * XY + (size_t)(x0 + r) * NY + yb0 + yl;
    __builtin_nontemporal_store(o0, (f4*)ob);
    __builtin_nontemporal_store(o1, (f4*)(ob + XY));
    __builtin_nontemporal_store(o2, (f4*)(ob + 2 * XY));
}

extern "C" void kernel_launch(void* const* d_in, const int* in_sizes, int n_in,
                              void* d_out, int out_size, void* d_ws, size_t ws_size,
                              hipStream_t stream) {
    const float* s  = (const float*)d_in[0];
    const float* t  = (const float*)d_in[1];
    const float* c0 = (const float*)d_in[2];
    float* out = (float*)d_out;

    psi11t_kernel<<<8192, 256, 0, stream>>>(s, t, c0, out);
}

// Round 8
// 179.183 us; speedup vs baseline: 1.3346x; 1.3346x over previous
//
#include <hip/hip_runtime.h>

#define NX 512
#define NY 512
#define XY (NX * NY)
#define LROW 272              // 8 left-halo + 256 main + 8 right-halo floats
#define NCH  1632             // 24 lds-rows * 68 f4-chunks

typedef float f4 __attribute__((ext_vector_type(4)));

#define GLOBAL_AS __attribute__((address_space(1)))
#define LDS_AS    __attribute__((address_space(3)))

// Clean concurrency test: 5 independent blocks/CU (vs r6's 2), everything
// else held at the proven-clean r6 recipe (two-phase b_lds, NO retention,
// gl_lds staging, aligned-b128-only LDS reads, 2 barriers).
// Block = 256 threads = 4 output rows x 256 y. s staged with +/-8 y-halo
// (no wrap logic in compute): 8 rows x 3c x 272 = 25.5 KB; b_lds 6x272 =
// 6.4 KB; total 32.6 KB -> 5 blocks/CU (20 waves, 62% occ potential).
// launch_bounds(256,5): VGPR cap 512/5 = 102 >> ~50 live -> NO SPILLS.
// (r2/r5/r7 rule: cap below live set => compiler spills, never drops occ.)
// Tripwires: WRITE_SIZE must be ~98.3 MB, FETCH ~55 MB.
__global__ __launch_bounds__(256, 5) void psi11t_kernel(
    const float* __restrict__ s,
    const float* __restrict__ t,
    const float* __restrict__ c0,
    float* __restrict__ out)
{
    __shared__ __align__(16) float s_lds[24 * LROW];  // [c*8+R][col], R <-> x0-2+R
    __shared__ __align__(16) float b_lds[6 * LROW];   // [br][col],   br <-> x0-1+br

    // 8192 blocks; XCD swizzle: each XCD (D%8) gets 1024 consecutive gids
    // = 4 whole batches (both y-halves of a strip stay on one XCD).
    const int D   = blockIdx.x;
    const int gid = (D & 7) * 1024 + (D >> 3);
    const int bidx  = gid >> 8;            // 32 batches
    const int rem   = gid & 255;
    const int half  = rem >> 7;            // y half
    const int strip = rem & 127;           // 128 strips of 4 rows
    const int x0  = strip * 4;
    const int yb0 = half * 256;

    const int tid = threadIdx.x;           // 256 threads
    const int yl  = (tid & 63) * 4;        // 0..252 local y offset

    const float* sb = s + (size_t)bidx * 3 * XY;

    // ---- Phase 1: stage s rows x0-2..x0+5 (+/-8 y-halo) via global_load_lds.
    // Chunk k: rc = k/68 = c*8+R, col = (k%68)*4. Dest linear in k (wave-
    // uniform base + lane*16); global src per-lane, 16B-aligned, no straddle.
    auto stage = [&](int k) {
        const int rc  = k / 68;
        const int col = (k - rc * 68) * 4;
        const int c   = rc >> 3;
        const int R   = rc & 7;
        const int xg  = (x0 - 2 + R + NX) & (NX - 1);
        const int y   = (yb0 - 8 + col + NY) & (NY - 1);
        __builtin_amdgcn_global_load_lds(
            (const GLOBAL_AS void*)(sb + (size_t)c * XY + (size_t)xg * NY + y),
            (LDS_AS void*)&s_lds[rc * LROW + col], 16, 0, 0);
    };
    #pragma unroll
    for (int q = 0; q < 6; ++q) stage(tid + q * 256);
    if (tid < 96) stage(tid + 1536);

    const float coeff = 2.0f * t[0] * c0[0];
    __syncthreads();                       // A: s_lds ready (vmcnt drained)

    // ---- Phase 2: b into b_lds. b row br <-> x = x0-1+br needs s lds-rows
    // br (up), br+1 (center), br+2 (dn). All reads aligned b128, halo'd.
    // Main: all 256 threads, br = 1 + (tid>>6) (centers x0..x0+3).
    const int rbm = 1 + (tid >> 6);
    f4 bc = {0.f, 0.f, 0.f, 0.f};          // retained into phase 3 (own row)
    #pragma unroll
    for (int c = 0; c < 3; ++c) {
        const float* SC = &s_lds[(c * 8 + rbm + 1) * LROW + 8 + yl];
        const f4 up = *(const f4*)&s_lds[(c * 8 + rbm) * LROW + 8 + yl];
        const f4 dn = *(const f4*)&s_lds[(c * 8 + rbm + 2) * LROW + 8 + yl];
        const f4 ce = *(const f4*)SC;
        const f4 pv = *(const f4*)(SC - 4);
        const f4 nx = *(const f4*)(SC + 4);
        const f4 shl = {pv[3], ce[0], ce[1], ce[2]};
        const f4 shr = {ce[1], ce[2], ce[3], nx[0]};
        bc += ce * (up + dn + shl + shr);
    }
    *(f4*)&b_lds[rbm * LROW + 8 + yl] = bc;

    // Halo b rows 0 and 5 (threads 0..127; wave-uniform split).
    if (tid < 128) {
        const int br = (tid < 64) ? 0 : 5;
        const int yl2 = (tid & 63) * 4;
        f4 acc = {0.f, 0.f, 0.f, 0.f};
        #pragma unroll
        for (int c = 0; c < 3; ++c) {
            const float* SC = &s_lds[(c * 8 + br + 1) * LROW + 8 + yl2];
            const f4 up = *(const f4*)&s_lds[(c * 8 + br) * LROW + 8 + yl2];
            const f4 dn = *(const f4*)&s_lds[(c * 8 + br + 2) * LROW + 8 + yl2];
            const f4 ce = *(const f4*)SC;
            const f4 pv = *(const f4*)(SC - 4);
            const f4 nx = *(const f4*)(SC + 4);
            const f4 shl = {pv[3], ce[0], ce[1], ce[2]};
            const f4 shr = {ce[1], ce[2], ce[3], nx[0]};
            acc += ce * (up + dn + shl + shr);
        }
        *(f4*)&b_lds[br * LROW + 8 + yl2] = acc;
    }

    // Edge-halo b f4s: 6 rows x 2 sides (local cols 4 and 264), 12 tasks.
    if (tid >= 128 && tid < 140) {
        const int idx  = tid - 128;
        const int hr   = idx >> 1;         // 0..5
        const int colb = (idx & 1) ? 264 : 4;
        f4 acc = {0.f, 0.f, 0.f, 0.f};
        #pragma unroll
        for (int c = 0; c < 3; ++c) {
            const float* SC = &s_lds[(c * 8 + hr + 1) * LROW + colb];
            const f4 up = *(const f4*)&s_lds[(c * 8 + hr) * LROW + colb];
            const f4 dn = *(const f4*)&s_lds[(c * 8 + hr + 2) * LROW + colb];
            const f4 ce = *(const f4*)SC;
            const f4 pv = *(const f4*)(SC - 4);
            const f4 nx = *(const f4*)(SC + 4);
            const f4 shl = {pv[3], ce[0], ce[1], ce[2]};
            const f4 shr = {ce[1], ce[2], ce[3], nx[0]};
            acc += ce * (up + dn + shl + shr);
        }
        *(f4*)&b_lds[hr * LROW + colb] = acc;
    }
    __syncthreads();                       // B: b_lds ready

    // ---- Phase 3: output row x0+r (r = tid>>6). s center lds-row r+2,
    // up r+1, dn r+3; b center row r+1 (== this thread's bc), bu row r,
    // bd row r+2. All aligned b128.
    const int r = tid >> 6;
    const float* B = &b_lds[(r + 1) * LROW + 8 + yl];
    const f4 bu = *(const f4*)&b_lds[r * LROW + 8 + yl];
    const f4 bd = *(const f4*)&b_lds[(r + 2) * LROW + 8 + yl];
    const f4 bp = *(const f4*)(B - 4);
    const f4 bn = *(const f4*)(B + 4);
    const f4 bshl = {bp[3], bc[0], bc[1], bc[2]};
    const f4 bshr = {bc[1], bc[2], bc[3], bn[0]};

    f4 G[3], cen[3];
    #pragma unroll
    for (int c = 0; c < 3; ++c) {
        const float* SC = &s_lds[(c * 8 + r + 2) * LROW + 8 + yl];
        const f4 up = *(const f4*)&s_lds[(c * 8 + r + 1) * LROW + 8 + yl];
        const f4 dn = *(const f4*)&s_lds[(c * 8 + r + 3) * LROW + 8 + yl];
        const f4 ce = *(const f4*)SC;
        const f4 pv = *(const f4*)(SC - 4);
        const f4 nx = *(const f4*)(SC + 4);
        const f4 shl = {pv[3], ce[0], ce[1], ce[2]};
        const f4 shr = {ce[1], ce[2], ce[3], nx[0]};
        const f4 Fs = up + dn + shl + shr;
        G[c] = Fs * bc + up * bu + dn * bd + shl * bshl + shr * bshr;
        cen[c] = ce;
    }

    const f4 o0 = (cen[1] * G[2] - cen[2] * G[1]) * coeff;
    const f4 o1 = (cen[2] * G[0] - cen[0] * G[2]) * coeff;
    const f4 o2 = (cen[0] * G[1] - cen[1] * G[0]) * coeff;

    float* ob = out + (size_t)bidx * 3 * XY + (size_t)(x0 + r) * NY + yb0 + yl;
    __builtin_nontemporal_store(o0, (f4*)ob);
    __builtin_nontemporal_store(o1, (f4*)(ob + XY));
    __builtin_nontemporal_store(o2, (f4*)(ob + 2 * XY));
}

extern "C" void kernel_launch(void* const* d_in, const int* in_sizes, int n_in,
                              void* d_out, int out_size, void* d_ws, size_t ws_size,
                              hipStream_t stream) {
    const float* s  = (const float*)d_in[0];
    const float* t  = (const float*)d_in[1];
    const float* c0 = (const float*)d_in[2];
    float* out = (float*)d_out;

    psi11t_kernel<<<8192, 256, 0, stream>>>(s, t, c0, out);
}